// Round 4
// baseline (779.648 us; speedup 1.0000x reference)
//
#include <hip/hip_runtime.h>
#include <math.h>

// Problem constants
#define BGRAPH 64
#define NNODE  512
#define NTOT   32768        // BGRAPH*NNODE
#define CIN    128
#define HDIM   128
#define EDIM_  5
#define EDGES  524288
#define K1C    256
#define K2C    128

using f32x4 = __attribute__((ext_vector_type(4))) float;
using s16x8 = __attribute__((ext_vector_type(8))) short;

__device__ __forceinline__ short f2bf(float f) {
    union { float f; unsigned u; } v; v.f = f;
    unsigned r = v.u + 0x7fffu + ((v.u >> 16) & 1u);   // RNE
    return (short)(r >> 16);
}
__device__ __forceinline__ float bf2f(short s) {
    union { unsigned u; float f; } v; v.u = ((unsigned)(unsigned short)s) << 16;
    return v.f;
}

// ---------------------------------------------------------------------------
// BatchNorm statistics
// ---------------------------------------------------------------------------
__global__ __launch_bounds__(256) void bn_stats_kernel(const float* __restrict__ x,
                                                       float* __restrict__ sum,
                                                       float* __restrict__ sumsq) {
    int c = threadIdx.x & 127;
    float s = 0.f, q = 0.f;
    const long total = (long)NTOT * CIN;
    for (long i = (long)blockIdx.x * 256 + threadIdx.x; i < total; i += (long)gridDim.x * 256) {
        float v = x[i];
        s += v; q += v * v;
    }
    __shared__ float ls[256], lq[256];
    ls[threadIdx.x] = s; lq[threadIdx.x] = q;
    __syncthreads();
    if (threadIdx.x < 128) {
        atomicAdd(&sum[c], ls[threadIdx.x] + ls[threadIdx.x + 128]);
        atomicAdd(&sumsq[c], lq[threadIdx.x] + lq[threadIdx.x + 128]);
    }
}

__global__ __launch_bounds__(128) void bn_finalize_kernel(const float* __restrict__ sum,
                                                          const float* __restrict__ sumsq,
                                                          const float* __restrict__ gamma,
                                                          const float* __restrict__ beta,
                                                          float* __restrict__ scale,
                                                          float* __restrict__ shift) {
    int c = threadIdx.x;
    float mu  = sum[c] / (float)NTOT;
    float var = sumsq[c] / (float)NTOT - mu * mu;
    float rstd = rsqrtf(var + 1e-5f);
    float sc = gamma[c] * rstd;
    scale[c] = sc;
    shift[c] = beta[c] - mu * sc;
}

// ---------------------------------------------------------------------------
// Pack Wq|Wk|Wv|Wskip into [128,512] and biases into [512]
// ---------------------------------------------------------------------------
__global__ __launch_bounds__(256) void pack_w4_kernel(const float* __restrict__ Wq, const float* __restrict__ Wk,
                                                      const float* __restrict__ Wv, const float* __restrict__ Ws,
                                                      const float* __restrict__ bq, const float* __restrict__ bk,
                                                      const float* __restrict__ bv, const float* __restrict__ bs,
                                                      float* __restrict__ W4, float* __restrict__ bias4) {
    int i = blockIdx.x * 256 + threadIdx.x;
    if (i < 128 * 512) {
        int k = i / 512, j = i % 512;
        float v;
        if (j < 128)      v = Wq[k * 128 + j];
        else if (j < 256) v = Wk[k * 128 + (j - 128)];
        else if (j < 384) v = Wv[k * 128 + (j - 256)];
        else              v = Ws[k * 128 + (j - 384)];
        W4[i] = v;
    }
    if (i < 512) {
        float v;
        if (i < 128)      v = bq[i];
        else if (i < 256) v = bk[i - 128];
        else if (i < 384) v = bv[i - 256];
        else              v = bs[i - 384];
        bias4[i] = v;
    }
}

// ---------------------------------------------------------------------------
// CSR build: histogram, scan, scatter
// ---------------------------------------------------------------------------
__global__ __launch_bounds__(256) void hist_kernel(const int* __restrict__ ei,
                                                   int* __restrict__ deg_src,
                                                   int* __restrict__ deg_dst) {
    int e = blockIdx.x * 256 + threadIdx.x;
    if (e < EDGES) {
        atomicAdd(&deg_src[ei[e]], 1);
        atomicAdd(&deg_dst[ei[EDGES + e]], 1);
    }
}

__global__ __launch_bounds__(1024) void scan_kernel(const int* __restrict__ deg,
                                                    int* __restrict__ rowptr,
                                                    int* __restrict__ cursor) {
    __shared__ int part[1024];
    int tid = threadIdx.x;
    int base = tid * 32;
    int s = 0;
    for (int i = 0; i < 32; ++i) s += deg[base + i];
    part[tid] = s;
    __syncthreads();
    for (int off = 1; off < 1024; off <<= 1) {
        int v = part[tid];
        int add = (tid >= off) ? part[tid - off] : 0;
        __syncthreads();
        part[tid] = v + add;
        __syncthreads();
    }
    int run = (tid == 0) ? 0 : part[tid - 1];
    for (int i = 0; i < 32; ++i) {
        rowptr[base + i] = run;
        cursor[base + i] = run;
        run += deg[base + i];
    }
}

__global__ __launch_bounds__(256) void scatter_kernel(const int* __restrict__ ei,
                                                      int* __restrict__ cur_src, int* __restrict__ cur_dst,
                                                      int* __restrict__ eid_src, int* __restrict__ eid_dst) {
    int e = blockIdx.x * 256 + threadIdx.x;
    if (e < EDGES) {
        int s = ei[e], d = ei[EDGES + e];
        eid_src[atomicAdd(&cur_src[s], 1)] = e;
        eid_dst[atomicAdd(&cur_dst[d], 1)] = e;
    }
}

// ---------------------------------------------------------------------------
// BF16 MFMA GEMM, fp32 global inputs (converted at staging): see round 3.
// OBF16: epilogue stores bf16 instead of fp32.
// ---------------------------------------------------------------------------
template <bool TRANS_A, bool AFFINE, bool RELU, bool DUAL, bool OBF16>
__global__ __launch_bounds__(256) void mgemm(const float* __restrict__ A,
                                             const float* __restrict__ B,
                                             const float* __restrict__ A2,
                                             const float* __restrict__ B2,
                                             int Ksplit,
                                             const float* __restrict__ bias,
                                             void* __restrict__ Cv,
                                             const float* __restrict__ scale,
                                             const float* __restrict__ shift,
                                             int M, int Nc, int K,
                                             int lda, int ldb, int ldc,
                                             long sA, long sB, long sC) {
    __shared__ __align__(16) short As[128 * 40];
    __shared__ __align__(16) short Bs[128 * 40];
    A += (long)blockIdx.z * sA;
    B += (long)blockIdx.z * sB;
    float* C = (float*)Cv + (OBF16 ? 0 : (long)blockIdx.z * sC);
    short* Cs = (short*)Cv + (OBF16 ? (long)blockIdx.z * sC : 0);
    const int m0 = blockIdx.y * 128, n0 = blockIdx.x * 128;
    const int tid = threadIdx.x;
    const int lane16 = tid & 15;
    const int quad = (tid & 63) >> 4;
    const int wrow = (tid >> 6) >> 1, wcol = (tid >> 6) & 1;

    f32x4 acc[4][4] = {};

    for (int k0 = 0; k0 < K; k0 += 32) {
        const float* Au = A; const float* Bu = B; int ku = k0;
        if (DUAL && k0 >= Ksplit) { Au = A2; Bu = B2; ku = k0 - Ksplit; }

        if (!TRANS_A) {
#pragma unroll
            for (int p = 0; p < 4; ++p) {
                int idx = tid + p * 256;
                int row = idx >> 3, c4 = idx & 7;
                float4 v = *(const float4*)(Au + (long)(m0 + row) * lda + ku + c4 * 4);
                if (AFFINE) {
                    int k = ku + c4 * 4;
                    v.x = v.x * scale[k] + shift[k];
                    v.y = v.y * scale[k + 1] + shift[k + 1];
                    v.z = v.z * scale[k + 2] + shift[k + 2];
                    v.w = v.w * scale[k + 3] + shift[k + 3];
                }
                *(short4*)&As[row * 40 + c4 * 4] =
                    make_short4(f2bf(v.x), f2bf(v.y), f2bf(v.z), f2bf(v.w));
            }
        } else {
            int c4 = tid & 31, g = tid >> 5;
            const float* src = Au + (long)(ku + g * 4) * lda + m0 + c4 * 4;
            float4 r0 = *(const float4*)(src);
            float4 r1 = *(const float4*)(src + lda);
            float4 r2 = *(const float4*)(src + 2 * lda);
            float4 r3 = *(const float4*)(src + 3 * lda);
            short* d = &As[(c4 * 4) * 40 + g * 4];
            *(short4*)(d + 0 * 40) = make_short4(f2bf(r0.x), f2bf(r1.x), f2bf(r2.x), f2bf(r3.x));
            *(short4*)(d + 1 * 40) = make_short4(f2bf(r0.y), f2bf(r1.y), f2bf(r2.y), f2bf(r3.y));
            *(short4*)(d + 2 * 40) = make_short4(f2bf(r0.z), f2bf(r1.z), f2bf(r2.z), f2bf(r3.z));
            *(short4*)(d + 3 * 40) = make_short4(f2bf(r0.w), f2bf(r1.w), f2bf(r2.w), f2bf(r3.w));
        }
        {
            int c4 = tid & 31, g = tid >> 5;
            const float* src = Bu + (long)(ku + g * 4) * ldb + n0 + c4 * 4;
            float4 r0 = *(const float4*)(src);
            float4 r1 = *(const float4*)(src + ldb);
            float4 r2 = *(const float4*)(src + 2 * ldb);
            float4 r3 = *(const float4*)(src + 3 * ldb);
            short* d = &Bs[(c4 * 4) * 40 + g * 4];
            *(short4*)(d + 0 * 40) = make_short4(f2bf(r0.x), f2bf(r1.x), f2bf(r2.x), f2bf(r3.x));
            *(short4*)(d + 1 * 40) = make_short4(f2bf(r0.y), f2bf(r1.y), f2bf(r2.y), f2bf(r3.y));
            *(short4*)(d + 2 * 40) = make_short4(f2bf(r0.z), f2bf(r1.z), f2bf(r2.z), f2bf(r3.z));
            *(short4*)(d + 3 * 40) = make_short4(f2bf(r0.w), f2bf(r1.w), f2bf(r2.w), f2bf(r3.w));
        }
        __syncthreads();

        s16x8 af[4], bf[4];
#pragma unroll
        for (int t = 0; t < 4; ++t) {
            af[t] = *(const s16x8*)&As[(wrow * 64 + t * 16 + lane16) * 40 + quad * 8];
            bf[t] = *(const s16x8*)&Bs[(wcol * 64 + t * 16 + lane16) * 40 + quad * 8];
        }
#pragma unroll
        for (int i = 0; i < 4; ++i)
#pragma unroll
            for (int j = 0; j < 4; ++j)
                acc[i][j] = __builtin_amdgcn_mfma_f32_16x16x32_bf16(af[i], bf[j], acc[i][j], 0, 0, 0);
        __syncthreads();
    }

#pragma unroll
    for (int i = 0; i < 4; ++i) {
        int gm = m0 + wrow * 64 + i * 16 + quad * 4;
#pragma unroll
        for (int j = 0; j < 4; ++j) {
            int gn = n0 + wcol * 64 + j * 16 + lane16;
            float bv = bias ? bias[gn] : 0.f;
#pragma unroll
            for (int r = 0; r < 4; ++r) {
                float val = acc[i][j][r] + bv;
                if (RELU) val = fmaxf(val, 0.f);
                if (OBF16) Cs[(long)(gm + r) * ldc + gn] = f2bf(val);
                else       C[(long)(gm + r) * ldc + gn] = val;
            }
        }
    }
}

// ---------------------------------------------------------------------------
// BF16-input MFMA GEMM (no conversion): C = outscale * (A @ B), batched.
// A: [M,K] bf16 row-major (lda). TRANS_B: B [N,K] row-major (Q@K^T style).
// !TRANS_B: B [K,N] k-major. C fp32 (ldc).
// ---------------------------------------------------------------------------
template <bool TRANS_B>
__global__ __launch_bounds__(256) void bgemm(const short* __restrict__ A,
                                             const short* __restrict__ B,
                                             float* __restrict__ C,
                                             float outscale,
                                             int M, int Nc, int K,
                                             int lda, int ldb, int ldc,
                                             long sA, long sB, long sC) {
    __shared__ __align__(16) short As[128 * 40];
    __shared__ __align__(16) short Bs[128 * 40];
    A += (long)blockIdx.z * sA;
    B += (long)blockIdx.z * sB;
    C += (long)blockIdx.z * sC;
    const int m0 = blockIdx.y * 128, n0 = blockIdx.x * 128;
    const int tid = threadIdx.x;
    const int lane16 = tid & 15;
    const int quad = (tid & 63) >> 4;
    const int wrow = (tid >> 6) >> 1, wcol = (tid >> 6) & 1;

    f32x4 acc[4][4] = {};

    for (int k0 = 0; k0 < K; k0 += 32) {
#pragma unroll
        for (int p = 0; p < 2; ++p) {           // A: direct bf16 copy
            int u = tid + p * 256;
            int row = u >> 2, g = u & 3;
            *(s16x8*)&As[row * 40 + g * 8] =
                *(const s16x8*)(A + (long)(m0 + row) * lda + k0 + g * 8);
        }
        if (TRANS_B) {
#pragma unroll
            for (int p = 0; p < 2; ++p) {       // B rows are n: direct copy
                int u = tid + p * 256;
                int row = u >> 2, g = u & 3;
                *(s16x8*)&Bs[row * 40 + g * 8] =
                    *(const s16x8*)(B + (long)(n0 + row) * ldb + k0 + g * 8);
            }
        } else {                                 // B [k][n]: transpose-stage
            int c4 = tid & 31, g = tid >> 5;
            const short* src = B + (long)(k0 + g * 4) * ldb + n0 + c4 * 4;
            short4 r0 = *(const short4*)(src);
            short4 r1 = *(const short4*)(src + ldb);
            short4 r2 = *(const short4*)(src + 2 * ldb);
            short4 r3 = *(const short4*)(src + 3 * ldb);
            short* d = &Bs[(c4 * 4) * 40 + g * 4];
            *(short4*)(d + 0 * 40) = make_short4(r0.x, r1.x, r2.x, r3.x);
            *(short4*)(d + 1 * 40) = make_short4(r0.y, r1.y, r2.y, r3.y);
            *(short4*)(d + 2 * 40) = make_short4(r0.z, r1.z, r2.z, r3.z);
            *(short4*)(d + 3 * 40) = make_short4(r0.w, r1.w, r2.w, r3.w);
        }
        __syncthreads();

        s16x8 af[4], bf[4];
#pragma unroll
        for (int t = 0; t < 4; ++t) {
            af[t] = *(const s16x8*)&As[(wrow * 64 + t * 16 + lane16) * 40 + quad * 8];
            bf[t] = *(const s16x8*)&Bs[(wcol * 64 + t * 16 + lane16) * 40 + quad * 8];
        }
#pragma unroll
        for (int i = 0; i < 4; ++i)
#pragma unroll
            for (int j = 0; j < 4; ++j)
                acc[i][j] = __builtin_amdgcn_mfma_f32_16x16x32_bf16(af[i], bf[j], acc[i][j], 0, 0, 0);
        __syncthreads();
    }

#pragma unroll
    for (int i = 0; i < 4; ++i) {
        int gm = m0 + wrow * 64 + i * 16 + quad * 4;
#pragma unroll
        for (int j = 0; j < 4; ++j) {
            int gn = n0 + wcol * 64 + j * 16 + lane16;
#pragma unroll
            for (int r = 0; r < 4; ++r)
                C[(long)(gm + r) * ldc + gn] = acc[i][j][r] * outscale;
        }
    }
}

// ---------------------------------------------------------------------------
// qWe[node][d] = (q[node,:] . We[d,:]) / sqrt(H)   (q bf16 in qkvs)
// ---------------------------------------------------------------------------
__global__ __launch_bounds__(256) void qwe_kernel(const short* __restrict__ qkvs,
                                                  const float* __restrict__ We,
                                                  float* __restrict__ qWe) {
    __shared__ float sWe[EDIM_ * 128];
    for (int i = threadIdx.x; i < EDIM_ * 128; i += 256) sWe[i] = We[i];
    __syncthreads();
    int node = blockIdx.x * 256 + threadIdx.x;
    const short* q = qkvs + (long)node * 512;
    float acc[EDIM_] = {};
    for (int c = 0; c < 128; ++c) {
        float qc = bf2f(q[c]);
#pragma unroll
        for (int d = 0; d < EDIM_; ++d) acc[d] += qc * sWe[d * 128 + c];
    }
    const float inv_sqrt_h = 0.08838834764831845f;
#pragma unroll
    for (int d = 0; d < EDIM_; ++d) qWe[node * EDIM_ + d] = acc[d] * inv_sqrt_h;
}

// ---------------------------------------------------------------------------
// Edge softmax, two-pass, one thread per dst node.
// logit(e) = S[dst, src_local] + dot5(eattr[e], qWe[dst])   (S pre-scaled)
// Writes unnormalized alpha[e], inv_l[dst], unnormalized ea5[dst][5].
// ---------------------------------------------------------------------------
__global__ __launch_bounds__(256) void esoftmax_kernel(const float* __restrict__ S,
                                                       const int* __restrict__ ei,
                                                       const float* __restrict__ eattr,
                                                       const float* __restrict__ qWe,
                                                       const int* __restrict__ rp_dst,
                                                       const int* __restrict__ deg_dst,
                                                       const int* __restrict__ eid_dst,
                                                       float* __restrict__ alpha,
                                                       float* __restrict__ inv_l,
                                                       float* __restrict__ ea5) {
    int node = blockIdx.x * 256 + threadIdx.x;
    const float* Srow = S + (long)node * 512;
    float qw[EDIM_];
#pragma unroll
    for (int d = 0; d < EDIM_; ++d) qw[d] = qWe[node * EDIM_ + d];
    int start = rp_dst[node], cnt = deg_dst[node];
    float m = -INFINITY;
    for (int t = 0; t < cnt; ++t) {
        int e = eid_dst[start + t];
        int src = ei[e] & 511;
        float lg = Srow[src];
#pragma unroll
        for (int d = 0; d < EDIM_; ++d) lg += eattr[e * EDIM_ + d] * qw[d];
        m = fmaxf(m, lg);
    }
    float l = 0.f, a5[EDIM_] = {};
    for (int t = 0; t < cnt; ++t) {
        int e = eid_dst[start + t];
        int src = ei[e] & 511;
        float lg = Srow[src];
        float ea[EDIM_];
#pragma unroll
        for (int d = 0; d < EDIM_; ++d) { ea[d] = eattr[e * EDIM_ + d]; lg += ea[d] * qw[d]; }
        float wv = expf(lg - m);
        l += wv;
        alpha[e] = wv;
#pragma unroll
        for (int d = 0; d < EDIM_; ++d) a5[d] += wv * ea[d];
    }
    inv_l[node] = (l > 0.f) ? 1.f / l : 0.f;
#pragma unroll
    for (int d = 0; d < EDIM_; ++d) ea5[node * EDIM_ + d] = a5[d];
}

// ---------------------------------------------------------------------------
// P[dst, src_local] += alpha[e]*inv_l[dst]  (bf16, per-dst-row serial; P pre-zeroed)
// ---------------------------------------------------------------------------
__global__ __launch_bounds__(256) void pbuild_kernel(const float* __restrict__ alpha,
                                                     const float* __restrict__ inv_l,
                                                     const int* __restrict__ ei,
                                                     const int* __restrict__ rp_dst,
                                                     const int* __restrict__ deg_dst,
                                                     const int* __restrict__ eid_dst,
                                                     short* __restrict__ P) {
    int node = blockIdx.x * 256 + threadIdx.x;
    short* Prow = P + (long)node * 512;
    float il = inv_l[node];
    int start = rp_dst[node], cnt = deg_dst[node];
    for (int t = 0; t < cnt; ++t) {
        int e = eid_dst[start + t];
        int src = ei[e] & 511;
        Prow[src] = f2bf(bf2f(Prow[src]) + alpha[e] * il);
    }
}

// ---------------------------------------------------------------------------
// h = relu(agg + inv_l * (ea5 @ We) + skip)   (in place over agg)
// ---------------------------------------------------------------------------
__global__ __launch_bounds__(256) void hassemble_kernel(float* __restrict__ h,
                                                        const float* __restrict__ ea5,
                                                        const float* __restrict__ inv_l,
                                                        const float* __restrict__ We,
                                                        const short* __restrict__ qkvs) {
    long i = (long)blockIdx.x * 256 + threadIdx.x;   // over NTOT*128
    int node = (int)(i >> 7);
    int c = (int)(i & 127);
    float ecorr = 0.f;
#pragma unroll
    for (int d = 0; d < EDIM_; ++d) ecorr += ea5[node * EDIM_ + d] * We[d * 128 + c];
    float v = h[i] + inv_l[node] * ecorr + bf2f(qkvs[(long)node * 512 + 384 + c]);
    h[i] = fmaxf(v, 0.f);
}

// ---------------------------------------------------------------------------
// Row-wise softmax over NC columns, wave per row
// ---------------------------------------------------------------------------
template <int NC>
__global__ __launch_bounds__(256) void softmax_kernel(float* __restrict__ s) {
    int wave = threadIdx.x >> 6;
    int lane = threadIdx.x & 63;
    int row = blockIdx.x * 4 + wave;
    float* p = s + (long)row * NC;
    constexpr int PER = NC / 64;
    float v[PER];
    float mx = -INFINITY;
#pragma unroll
    for (int j = 0; j < PER; ++j) { v[j] = p[lane + j * 64]; mx = fmaxf(mx, v[j]); }
#pragma unroll
    for (int off = 32; off; off >>= 1) mx = fmaxf(mx, __shfl_xor(mx, off));
    float sm = 0.f;
#pragma unroll
    for (int j = 0; j < PER; ++j) { v[j] = expf(v[j] - mx); sm += v[j]; }
#pragma unroll
    for (int off = 32; off; off >>= 1) sm += __shfl_xor(sm, off);
    float inv = 1.f / sm;
#pragma unroll
    for (int j = 0; j < PER; ++j) p[lane + j * 64] = v[j] * inv;
}

// ---------------------------------------------------------------------------
// Sparse T1 = adj @ s1 via CSR-by-src
// ---------------------------------------------------------------------------
__global__ __launch_bounds__(256) void spmm_t1_kernel(const float* __restrict__ s1,
                                                      const int* __restrict__ ei_dst,
                                                      const int* __restrict__ rp_src,
                                                      const int* __restrict__ deg_src,
                                                      const int* __restrict__ eid_src,
                                                      float* __restrict__ T1) {
    int wave = threadIdx.x >> 6;
    int lane = threadIdx.x & 63;
    int node = blockIdx.x * 4 + wave;
    int start = rp_src[node], cnt = deg_src[node];
    float acc[4] = {0.f, 0.f, 0.f, 0.f};
    for (int t = 0; t < cnt; ++t) {
        int e = eid_src[start + t];
        int dst = ei_dst[e];
        const float* sr = s1 + (long)dst * K1C;
#pragma unroll
        for (int j = 0; j < 4; ++j) acc[j] += sr[lane + j * 64];
    }
    float* out = T1 + (long)node * K1C;
#pragma unroll
    for (int j = 0; j < 4; ++j) out[lane + j * 64] = acc[j];
}

// ---------------------------------------------------------------------------
// Pooled-adj normalization
// ---------------------------------------------------------------------------
template <int KC>
__global__ __launch_bounds__(256) void dinv_kernel(const float* __restrict__ adj,
                                                   float* __restrict__ dinv) {
    int wave = threadIdx.x >> 6;
    int lane = threadIdx.x & 63;
    int row = blockIdx.x * 4 + wave;
    int b = row / KC, r = row % KC;
    const float* p = adj + (long)b * KC * KC + (long)r * KC;
    float s = 0.f;
    for (int j = lane; j < KC; j += 64)
        if (j != r) s += p[j];
#pragma unroll
    for (int off = 32; off; off >>= 1) s += __shfl_xor(s, off);
    if (lane == 0) dinv[row] = 1.f / (sqrtf(s) + 1e-15f);
}

template <int KC>
__global__ __launch_bounds__(256) void scale_adj_kernel(float* __restrict__ adj,
                                                        const float* __restrict__ dinv) {
    long i = (long)blockIdx.x * 256 + threadIdx.x;
    int c = (int)(i % KC);
    long t = i / KC;
    int r = (int)(t % KC);
    int b = (int)(t / KC);
    float v = adj[i];
    v = (r == c) ? 0.f : v * dinv[b * KC + r] * dinv[b * KC + c];
    adj[i] = v;
}

// ---------------------------------------------------------------------------
// Readout
// ---------------------------------------------------------------------------
__global__ __launch_bounds__(128) void readout_kernel(const float* __restrict__ xd3,
                                                      const float* __restrict__ W_lin1,
                                                      const float* __restrict__ b_lin1,
                                                      const float* __restrict__ W_ro,
                                                      const float* __restrict__ b_ro,
                                                      float* __restrict__ out) {
    int b = blockIdx.x, t = threadIdx.x;
    __shared__ float g[128], g2[128], wred[2];
    const float* X = xd3 + (long)b * K2C * 128;
    float s = 0.f;
    for (int r = 0; r < K2C; ++r) s += X[r * 128 + t];
    g[t] = s * (1.f / (float)K2C);
    __syncthreads();
    float u = b_lin1[t];
    for (int k = 0; k < 128; ++k) u += g[k] * W_lin1[k * 128 + t];
    g2[t] = fmaxf(u, 0.f);
    __syncthreads();
    float p = g2[t] * W_ro[t];
#pragma unroll
    for (int off = 32; off; off >>= 1) p += __shfl_xor(p, off);
    if ((t & 63) == 0) wred[t >> 6] = p;
    __syncthreads();
    if (t == 0) {
        float tot = wred[0] + wred[1] + b_ro[0];
        out[b] = 1.f / (1.f + expf(-tot));
    }
}

// ---------------------------------------------------------------------------
extern "C" void kernel_launch(void* const* d_in, const int* in_sizes, int n_in,
                              void* d_out, int out_size, void* d_ws, size_t ws_size,
                              hipStream_t stream) {
    const float* x      = (const float*)d_in[0];
    const int*   ei     = (const int*)d_in[1];
    const float* eattr  = (const float*)d_in[2];
    const float* gamma  = (const float*)d_in[4];
    const float* beta   = (const float*)d_in[5];
    const float* Wq     = (const float*)d_in[6];
    const float* bq     = (const float*)d_in[7];
    const float* Wk     = (const float*)d_in[8];
    const float* bk     = (const float*)d_in[9];
    const float* Wv     = (const float*)d_in[10];
    const float* bv     = (const float*)d_in[11];
    const float* We     = (const float*)d_in[12];
    const float* Wskip  = (const float*)d_in[13];
    const float* bskip  = (const float*)d_in[14];
    const float* W_mlp1 = (const float*)d_in[15];
    const float* b_mlp1 = (const float*)d_in[16];
    const float* W2_rel = (const float*)d_in[17];
    const float* b2_rel = (const float*)d_in[18];
    const float* W2_root= (const float*)d_in[19];
    const float* W_mlp2 = (const float*)d_in[20];
    const float* b_mlp2 = (const float*)d_in[21];
    const float* W3_rel = (const float*)d_in[22];
    const float* b3_rel = (const float*)d_in[23];
    const float* W3_root= (const float*)d_in[24];
    const float* W_lin1 = (const float*)d_in[25];
    const float* b_lin1 = (const float*)d_in[26];
    const float* W_ro   = (const float*)d_in[27];
    const float* b_ro   = (const float*)d_in[28];
    float* out = (float*)d_out;

    char* w = (char*)d_ws;
    const size_t MB = 1ull << 20;
    // Workspace plan (peak 110 MB), lifetime-aliased:
    //  [0,32)   qkvs bf16 (steps 4-8, skip alive till h-assemble) → s1 fp32 (step 9+)
    //  [32,96)  S fp32 (QK^T, dead after esoftmax)
    //  [32,64)  P bf16 (over dead S) → T1 fp32 (step 12) → tgc2/xd2/s2/t2 sub-blocks
    //  [0,16)   adj2/xp2/t3/xd3 (after s1 dead)
    //  [64,80)  agg/h fp32 (over dead upper-S)
    //  [80,96)  adj1
    //  [96,104) attn temporaries (alpha/inv_l/ea5/qWe) → xp1 (after attn done)
    //  [104,110) misc
    short* qkvs = (short*)(w + 0);          // [NTOT,512] bf16 32MB
    float* s1   = (float*)(w + 0);          // [NTOT,256] 32MB
    float* S    = (float*)(w + 32 * MB);    // [NTOT,512] 64MB
    short* P    = (short*)(w + 32 * MB);    // [NTOT,512] bf16 32MB
    float* T1   = (float*)(w + 32 * MB);    // [NTOT,256] 32MB
    float* tgc2 = (float*)(w + 32 * MB);    // [B,256,128] 8MB
    float* xd2  = (float*)(w + 40 * MB);    // [B,256,128] 8MB
    float* s2   = (float*)(w + 48 * MB);    // [B,256,128] 8MB
    float* t2   = (float*)(w + 56 * MB);    // [B,256,128] 8MB
    float* adj2 = (float*)(w + 0);          // [B,128,128] 4MB
    float* xp2  = (float*)(w + 4 * MB);     // [B,128,128] 4MB
    float* t3   = (float*)(w + 8 * MB);     // [B,128,128] 4MB
    float* xd3  = (float*)(w + 12 * MB);    // [B,128,128] 4MB
    float* h    = (float*)(w + 64 * MB);    // [NTOT,128] 16MB (agg then h)
    float* adj1 = (float*)(w + 80 * MB);    // [B,256,256] 16MB
    float* xp1  = (float*)(w + 96 * MB);    // [B,256,128] 8MB
    float* alpha = (float*)(w + 96 * MB);            // [E] 2MB (dead before xp1)
    float* inv_l = (float*)(w + 98 * MB);            // [NTOT] 128KB
    float* ea5   = (float*)(w + 98 * MB + 0x40000);  // [NTOT,5] 640KB
    float* qWe   = (float*)(w + 99 * MB);            // [NTOT,5] 640KB
    char* misc  = w + 104 * MB;
    float* W4     = (float*)(misc + 0x00000);
    float* bias4  = (float*)(misc + 0x40000);
    float* colsum = (float*)(misc + 0x41000);
    float* colsq  = (float*)(misc + 0x41200);
    float* scale  = (float*)(misc + 0x41400);
    float* shift  = (float*)(misc + 0x41600);
    float* dinv1  = (float*)(misc + 0x42000);
    float* dinv2  = (float*)(misc + 0x52000);
    int* deg_src  = (int*)(misc + 0x60000);
    int* deg_dst  = (int*)(misc + 0x80000);
    int* rp_src   = (int*)(misc + 0xA0000);
    int* rp_dst   = (int*)(misc + 0xC0000);
    int* cur_src  = (int*)(misc + 0xE0000);
    int* cur_dst  = (int*)(misc + 0x100000);
    int* eid_src  = (int*)(misc + 0x120000);
    int* eid_dst  = (int*)(misc + 0x320000);

    hipMemsetAsync(colsum, 0, 1024, stream);
    hipMemsetAsync(deg_src, 0, 2 * NTOT * sizeof(int), stream);

    // 1. BatchNorm affine params
    bn_stats_kernel<<<64, 256, 0, stream>>>(x, colsum, colsq);
    bn_finalize_kernel<<<1, 128, 0, stream>>>(colsum, colsq, gamma, beta, scale, shift);

    // 2. Pack fused qkvs weights
    pack_w4_kernel<<<256, 256, 0, stream>>>(Wq, Wk, Wv, Wskip, bq, bk, bv, bskip, W4, bias4);

    // 3. CSR by src and dst
    hist_kernel<<<EDGES / 256, 256, 0, stream>>>(ei, deg_src, deg_dst);
    scan_kernel<<<1, 1024, 0, stream>>>(deg_src, rp_src, cur_src);
    scan_kernel<<<1, 1024, 0, stream>>>(deg_dst, rp_dst, cur_dst);
    scatter_kernel<<<EDGES / 256, 256, 0, stream>>>(ei, cur_src, cur_dst, eid_src, eid_dst);

    // 4. qkvs(bf16) = BN(x) @ [Wq|Wk|Wv|Wskip] + biases
    mgemm<false, true, false, false, true><<<dim3(4, 256, 1), 256, 0, stream>>>(
        x, W4, nullptr, nullptr, 0, bias4, qkvs, scale, shift,
        NTOT, 512, 128, 128, 512, 512, 0, 0, 0);

    // 5. qWe = q @ We^T / sqrt(H)
    qwe_kernel<<<NTOT / 256, 256, 0, stream>>>(qkvs, We, qWe);

    // 6. S = (Q @ K^T) / sqrt(H) per graph (dense, MFMA)
    bgemm<true><<<dim3(4, 4, BGRAPH), 256, 0, stream>>>(
        qkvs + 0, qkvs + 128, S, 0.08838834764831845f,
        NNODE, NNODE, 128, 512, 512, 512,
        (long)NNODE * 512, (long)NNODE * 512, (long)NNODE * NNODE);

    // 7. Edge softmax (two-pass, thread per dst)
    esoftmax_kernel<<<NTOT / 256, 256, 0, stream>>>(
        S, ei, eattr, qWe, rp_dst, deg_dst, eid_dst, alpha, inv_l, ea5);

    // 8. Build P (bf16 alpha matrix) and agg = P @ V
    hipMemsetAsync(P, 0, (size_t)NTOT * 512 * sizeof(short), stream);
    pbuild_kernel<<<NTOT / 256, 256, 0, stream>>>(alpha, inv_l, ei, rp_dst, deg_dst, eid_dst, P);
    bgemm<false><<<dim3(1, 4, BGRAPH), 256, 0, stream>>>(
        P, qkvs + 256, h, 1.0f,
        NNODE, 128, NNODE, 512, 512, 128,
        (long)NNODE * 512, (long)NNODE * 512, (long)NNODE * 128);
    hassemble_kernel<<<(NTOT * 128) / 256, 256, 0, stream>>>(h, ea5, inv_l, We, qkvs);

    // 9. s1 = softmax(h @ W_mlp1 + b_mlp1)
    mgemm<false, false, false, false, false><<<dim3(2, 256, 1), 256, 0, stream>>>(
        h, W_mlp1, nullptr, nullptr, 0, b_mlp1, s1, nullptr, nullptr,
        NTOT, K1C, 128, 128, K1C, K1C, 0, 0, 0);
    softmax_kernel<K1C><<<NTOT / 4, 256, 0, stream>>>(s1);

    // 10. T1 = adj @ s1 (sparse)
    spmm_t1_kernel<<<NTOT / 4, 256, 0, stream>>>(s1, ei + EDGES, rp_src, deg_src, eid_src, T1);

    // 11. adj1 = s1^T T1 ; xp1 = s1^T h
    mgemm<true, false, false, false, false><<<dim3(2, 2, BGRAPH), 256, 0, stream>>>(
        s1, T1, nullptr, nullptr, 0, nullptr, adj1, nullptr, nullptr,
        K1C, K1C, NNODE, K1C, K1C, K1C,
        (long)NNODE * K1C, (long)NNODE * K1C, (long)K1C * K1C);
    mgemm<true, false, false, false, false><<<dim3(1, 2, BGRAPH), 256, 0, stream>>>(
        s1, h, nullptr, nullptr, 0, nullptr, xp1, nullptr, nullptr,
        K1C, 128, NNODE, K1C, 128, 128,
        (long)NNODE * K1C, (long)NNODE * 128, (long)K1C * 128);

    // 12. Normalize adj1
    dinv_kernel<K1C><<<(BGRAPH * K1C) / 4, 256, 0, stream>>>(adj1, dinv1);
    scale_adj_kernel<K1C><<<(BGRAPH * K1C * K1C) / 256, 256, 0, stream>>>(adj1, dinv1);

    // 13. GraphConv2
    mgemm<false, false, false, false, false><<<dim3(1, 2, BGRAPH), 256, 0, stream>>>(
        adj1, xp1, nullptr, nullptr, 0, nullptr, tgc2, nullptr, nullptr,
        K1C, 128, K1C, K1C, 128, 128,
        (long)K1C * K1C, (long)K1C * 128, (long)K1C * 128);
    mgemm<false, false, true, true, false><<<dim3(1, 128, 1), 256, 0, stream>>>(
        tgc2, W2_rel, xp1, W2_root, 128, b2_rel, xd2, nullptr, nullptr,
        BGRAPH * K1C, 128, 256, 128, 128, 128, 0, 0, 0);

    // 14. s2 = softmax(xd2 @ W_mlp2 + b_mlp2)
    mgemm<false, false, false, false, false><<<dim3(1, 128, 1), 256, 0, stream>>>(
        xd2, W_mlp2, nullptr, nullptr, 0, b_mlp2, s2, nullptr, nullptr,
        BGRAPH * K1C, K2C, 128, 128, K2C, K2C, 0, 0, 0);
    softmax_kernel<K2C><<<(BGRAPH * K1C) / 4, 256, 0, stream>>>(s2);

    // 15. Pool2
    mgemm<false, false, false, false, false><<<dim3(1, 2, BGRAPH), 256, 0, stream>>>(
        adj1, s2, nullptr, nullptr, 0, nullptr, t2, nullptr, nullptr,
        K1C, K2C, K1C, K1C, K2C, K2C,
        (long)K1C * K1C, (long)K1C * K2C, (long)K1C * K2C);
    mgemm<true, false, false, false, false><<<dim3(1, 1, BGRAPH), 256, 0, stream>>>(
        s2, t2, nullptr, nullptr, 0, nullptr, adj2, nullptr, nullptr,
        K2C, K2C, K1C, K2C, K2C, K2C,
        (long)K1C * K2C, (long)K1C * K2C, (long)K2C * K2C);
    mgemm<true, false, false, false, false><<<dim3(1, 1, BGRAPH), 256, 0, stream>>>(
        s2, xd2, nullptr, nullptr, 0, nullptr, xp2, nullptr, nullptr,
        K2C, 128, K1C, K2C, 128, 128,
        (long)K1C * K2C, (long)K1C * 128, (long)K2C * 128);

    // 16. Normalize adj2
    dinv_kernel<K2C><<<(BGRAPH * K2C) / 4, 256, 0, stream>>>(adj2, dinv2);
    scale_adj_kernel<K2C><<<(BGRAPH * K2C * K2C) / 256, 256, 0, stream>>>(adj2, dinv2);

    // 17. GraphConv3
    mgemm<false, false, false, false, false><<<dim3(1, 1, BGRAPH), 256, 0, stream>>>(
        adj2, xp2, nullptr, nullptr, 0, nullptr, t3, nullptr, nullptr,
        K2C, 128, K2C, K2C, 128, 128,
        (long)K2C * K2C, (long)K2C * 128, (long)K2C * 128);
    mgemm<false, false, false, true, false><<<dim3(1, 64, 1), 256, 0, stream>>>(
        t3, W3_rel, xp2, W3_root, 128, b3_rel, xd3, nullptr, nullptr,
        BGRAPH * K2C, 128, 256, 128, 128, 128, 0, 0, 0);

    // 18. Readout
    readout_kernel<<<BGRAPH, 128, 0, stream>>>(xd3, W_lin1, b_lin1, W_ro, b_ro, out);

    (void)in_sizes; (void)n_in; (void)out_size; (void)ws_size;
}